// Round 2
// baseline (111.260 us; speedup 1.0000x reference)
//
#include <hip/hip_runtime.h>

// Problem constants (match reference)
#define GS    20
#define PARAM 40
#define NSYS  80             // B * A = 8 * 10
#define NLOC  (GS * PARAM)   // 800 unknowns per system
#define NTH   400
#define INNER 5              // Jacobi sweeps for G=S^-1 Ng, c=S^-1 v (||B||~0.33); MUST be odd
#define OUTER 3              // block-preconditioned sweeps (rho ~ 0.15); R6/R7: absmax unchanged

// Solve (I (x) S + M (x) Ng) x = v, then clip to [-1,1].
// Block form, row i:  x_i = S^-1 v_i - (S^-1 Ng) sum_j M[i,j] x_j  =  c_i - G z_i
// Setup (inner): G and c via point-Jacobi on S (S' rows in VGPRs, G column-major in LDS).
// Outer: phase1 Z = M X (float4), phase2 x' = c - G Z (G rows in VGPRs).
//
// LESSONS (do not regress):
//  - R6: per-thread scalar global reads (stride 160B) are uncoalesced — keep ALL global
//    access as lane-contiguous float4.
//  - R6/R7: `#pragma unroll` on the INNER/OUTER sweep loops explodes live registers
//    -> scratch spills -> FETCH 2.4->11.8 MB, WRITE 0.25->22.5 MB, dispatch 14->48 us.
//    Keep sweep loops ROLLED.
//  - R8 (REGRESSION, 67.4->84.8 us): replacing the sr0..sr3 register arrays with
//    explicit per-k LDS pointer reads (fused/balanced sweep) quadrupled LDS issue in
//    the hot loop (20 -> 80 ds_read_b128 per sweep per thread). With rolled sweep
//    loops the compiler DOES keep S' rows register-resident across all 5 sweeps —
//    keep the sr0..sr3 structure. Balanced-c was worth only ~0.3 us; not worth it.
//  - R9: final inner sweep scatters G ROW-major (sGrow, 4 one-time scalar writes);
//    outer gather becomes 20 ds_read_b128 (was 80 scalar ds_read_b32). mrow staged
//    as float4[5]. These do not touch the inner loop. Keep sGrow padding at 11
//    float4s/row (stride 176B -> only p,p+8,p+16 alias; pad 12 would be 10-way).
__global__ __launch_bounds__(NTH) void gliam_solve(
    const float* __restrict__ mat,   // (NSYS, GS, GS)
    const float* __restrict__ val,   // (NSYS, GS, PARAM)
    const float* __restrict__ S,     // (PARAM, PARAM)
    const float* __restrict__ Ng,    // (PARAM, PARAM)
    float* __restrict__ out)         // (NSYS, GS, PARAM)
{
    __shared__ float4 sSoff[PARAM * 11];   // D^-1 S, diag zeroed, rows padded to 44 floats
    __shared__ float4 sNgP [PARAM * 11];   // raw Ng, padded
    __shared__ float  sRD  [PARAM];        // 1 / S[p][p]
    __shared__ float  sM   [GS * GS];
    __shared__ float4 sGc  [2][PARAM * 11]; // G column-major: col u at [u*11 .. u*11+9]
    __shared__ float4 sGrow[PARAM * 11];    // final G row-major: row r at [r*11 .. r*11+9]
    __shared__ float4 sXv  [2][NLOC / 4];   // state X (also c-iteration buffer)
    __shared__ float4 sZ   [NLOC / 4];      // Z = M·X

    const int sys = blockIdx.x;
    const int t   = threadIdx.x;
    const int pb  = t % 10;   // float4 row-block: rows 4pb..4pb+3
    const int u   = t / 10;   // 0..39: G column index; (u<20) also c system-row

    // ---- stage (coalesced float4) + fold D^-1 into S rows ----
    {
        const float rd = 1.0f / S[u * PARAM + u];    // 40 distinct addrs, L1 broadcast
        float4 a = ((const float4*)S)[t];            // row u, float4 block pb (coalesced)
        a.x *= rd; a.y *= rd; a.z *= rd; a.w *= rd;
        if (pb == (u >> 2)) ((float*)&a)[u & 3] = 0.0f;   // zero diagonal entry
        sSoff[u * 11 + pb] = a;
        sNgP [u * 11 + pb] = ((const float4*)Ng)[t]; // coalesced
    }
    if (t < PARAM) sRD[t] = 1.0f / S[t * PARAM + t];
    sM[t] = mat[sys * GS * GS + t];                  // GS*GS == NTH == 400, coalesced
    __syncthreads();

    // ---- per-thread registers: S' rows 4pb..4pb+3; Ngd/Vd constants for column u ----
    float4 sr0[10], sr1[10], sr2[10], sr3[10];
    float4 ngd, vd = make_float4(0.f, 0.f, 0.f, 0.f);
    {
        #pragma unroll
        for (int k = 0; k < 10; ++k) {
            sr0[k] = sSoff[(4*pb+0)*11 + k];
            sr1[k] = sSoff[(4*pb+1)*11 + k];
            sr2[k] = sSoff[(4*pb+2)*11 + k];
            sr3[k] = sSoff[(4*pb+3)*11 + k];
        }
        const float* Ngf = (const float*)sNgP;       // LDS transpose-gather (once)
        const float rd0 = sRD[4*pb+0], rd1 = sRD[4*pb+1],
                    rd2 = sRD[4*pb+2], rd3 = sRD[4*pb+3];
        ngd.x = Ngf[(4*pb+0)*44 + u] * rd0;
        ngd.y = Ngf[(4*pb+1)*44 + u] * rd1;
        ngd.z = Ngf[(4*pb+2)*44 + u] * rd2;
        ngd.w = Ngf[(4*pb+3)*44 + u] * rd3;
        sGc[0][u*11 + pb] = ngd;                     // G0 = D^-1 Ng (column-major)
        if (u < GS) {
            const float4 v4 = *(const float4*)&val[sys*NLOC + u*PARAM + 4*pb]; // coalesced
            vd.x = v4.x * rd0; vd.y = v4.y * rd1; vd.z = v4.z * rd2; vd.w = v4.w * rd3;
            sXv[0][u*10 + pb] = vd;                  // c0 = D^-1 v
        }
    }
    __syncthreads();

    // ---- inner sweeps (ROLLED): G <- Ngd - S'off G ;  c <- Vd - S'off c ----
    for (int s = 0; s < INNER; ++s) {
        const int cur = s & 1, nxt = cur ^ 1;
        float4 accG = ngd;
        float4 accC = vd;
        const float4* gcol = &sGc[cur][u * 11];
        #pragma unroll
        for (int k = 0; k < 10; ++k) {
            const float4 g = gcol[k];
            accG.x -= sr0[k].x*g.x + sr0[k].y*g.y + sr0[k].z*g.z + sr0[k].w*g.w;
            accG.y -= sr1[k].x*g.x + sr1[k].y*g.y + sr1[k].z*g.z + sr1[k].w*g.w;
            accG.z -= sr2[k].x*g.x + sr2[k].y*g.y + sr2[k].z*g.z + sr2[k].w*g.w;
            accG.w -= sr3[k].x*g.x + sr3[k].y*g.y + sr3[k].z*g.z + sr3[k].w*g.w;
        }
        if (u < GS) {
            const float4* ccol = &sXv[cur][u * 10];
            #pragma unroll
            for (int k = 0; k < 10; ++k) {
                const float4 c = ccol[k];
                accC.x -= sr0[k].x*c.x + sr0[k].y*c.y + sr0[k].z*c.z + sr0[k].w*c.w;
                accC.y -= sr1[k].x*c.x + sr1[k].y*c.y + sr1[k].z*c.z + sr1[k].w*c.w;
                accC.z -= sr2[k].x*c.x + sr2[k].y*c.y + sr2[k].z*c.z + sr2[k].w*c.w;
                accC.w -= sr3[k].x*c.x + sr3[k].y*c.y + sr3[k].z*c.z + sr3[k].w*c.w;
            }
        }
        if (s < INNER - 1) {
            sGc[nxt][u*11 + pb] = accG;              // column-major for next sweep
        } else {
            float* Gr = (float*)sGrow;               // final sweep: row-major scatter
            Gr[(4*pb+0)*44 + u] = accG.x;
            Gr[(4*pb+1)*44 + u] = accG.y;
            Gr[(4*pb+2)*44 + u] = accG.z;
            Gr[(4*pb+3)*44 + u] = accG.w;
        }
        if (u < GS) sXv[nxt][u*10 + pb] = accC;
        __syncthreads();
    }
    const int fin = INNER & 1;   // final c buffer index (== 1 for odd INNER)

    // ---- outer-loop registers: G rows p, p+20 (float4 reads); c values; M row ----
    const int i = t / GS;        // block-row 0..19
    const int p = t % GS;        // component 0..19; partner p+20
    float4 gr0[10], gr1[10];
    #pragma unroll
    for (int k = 0; k < 10; ++k) {
        gr0[k] = sGrow[ p      * 11 + k];
        gr1[k] = sGrow[(p + 20)* 11 + k];
    }
    const float c0 = ((const float*)sXv[fin])[i*PARAM + p];
    const float c1 = ((const float*)sXv[fin])[i*PARAM + p + 20];
    float4 mrow4[5];
    if (t < 200) {
        const int zi = t / 10;
        #pragma unroll
        for (int k = 0; k < 5; ++k) mrow4[k] = *(const float4*)&sM[zi*GS + 4*k];
    }
    // (reads only — all data final behind the last inner barrier; x0 = c in sXv[fin])

    int cur = fin;
    for (int it = 0; it < OUTER; ++it) {   // ROLLED (see header note)
        // phase 1: Z[zi][cc4] = sum_j M[zi,j] * X[j][cc4]  (j order preserved)
        if (t < 200) {
            const int zi = t / 10, cc = t - (t/10)*10;
            const float4* X4 = sXv[cur];
            float4 acc = make_float4(0.f, 0.f, 0.f, 0.f);
            #pragma unroll
            for (int jb = 0; jb < 5; ++jb) {
                const float4 m  = mrow4[jb];
                const float4 x0 = X4[(4*jb+0)*10 + cc];
                const float4 x1 = X4[(4*jb+1)*10 + cc];
                const float4 x2 = X4[(4*jb+2)*10 + cc];
                const float4 x3 = X4[(4*jb+3)*10 + cc];
                acc.x += m.x*x0.x; acc.y += m.x*x0.y; acc.z += m.x*x0.z; acc.w += m.x*x0.w;
                acc.x += m.y*x1.x; acc.y += m.y*x1.y; acc.z += m.y*x1.z; acc.w += m.y*x1.w;
                acc.x += m.z*x2.x; acc.y += m.z*x2.y; acc.z += m.z*x2.z; acc.w += m.z*x2.w;
                acc.x += m.w*x3.x; acc.y += m.w*x3.y; acc.z += m.w*x3.z; acc.w += m.w*x3.w;
            }
            sZ[zi*10 + cc] = acc;
        }
        __syncthreads();
        // phase 2: x'_{i,p} = c - Grow_p · Z_i  (two outputs share Z_i reads)
        const float4* Z4 = &sZ[i*10];
        float a0 = 0.f, a1 = 0.f;
        #pragma unroll
        for (int k = 0; k < 10; ++k) {
            const float4 z = Z4[k];
            a0 += gr0[k].x*z.x + gr0[k].y*z.y + gr0[k].z*z.z + gr0[k].w*z.w;
            a1 += gr1[k].x*z.x + gr1[k].y*z.y + gr1[k].z*z.z + gr1[k].w*z.w;
        }
        const float x0n = c0 - a0, x1n = c1 - a1;
        if (it == OUTER - 1) {
            // epilogue: advrelu(lo=-1,hi=1) == clip
            out[sys*NLOC + i*PARAM + p   ] = fminf(fmaxf(x0n, -1.f), 1.f);
            out[sys*NLOC + i*PARAM + p+20] = fminf(fmaxf(x1n, -1.f), 1.f);
        } else {
            ((float*)sXv[cur ^ 1])[i*PARAM + p   ] = x0n;
            ((float*)sXv[cur ^ 1])[i*PARAM + p+20] = x1n;
            __syncthreads();
            cur ^= 1;
        }
    }
}

extern "C" void kernel_launch(void* const* d_in, const int* in_sizes, int n_in,
                              void* d_out, int out_size, void* d_ws, size_t ws_size,
                              hipStream_t stream) {
    const float* mat = (const float*)d_in[0];  // 8*10*20*20 = 32000
    const float* val = (const float*)d_in[1];  // 8*10*20*40 = 64000
    const float* S   = (const float*)d_in[2];  // 40*40
    const float* Ng  = (const float*)d_in[3];  // 40*40
    float* out = (float*)d_out;                // 64000 f32

    gliam_solve<<<NSYS, NTH, 0, stream>>>(mat, val, S, Ng, out);
}

// Round 3
// 111.134 us; speedup vs baseline: 1.0011x; 1.0011x over previous
//
#include <hip/hip_runtime.h>

// Problem constants (match reference)
#define GS    20
#define PARAM 40
#define NSYS  80             // B * A = 8 * 10
#define NLOC  (GS * PARAM)   // 800 unknowns per system
#define NTH   400
#define INNER 5              // Jacobi sweeps for G=S^-1 Ng, c=S^-1 v (||B||~0.33); MUST be odd
#define OUTER 3              // block-preconditioned sweeps (rho ~ 0.15); R6/R7: absmax unchanged

// Solve (I (x) S + M (x) Ng) x = v, then clip to [-1,1].
// Block form, row i:  x_i = S^-1 v_i - (S^-1 Ng) sum_j M[i,j] x_j  =  c_i - G z_i
// Setup (inner): G and c via point-Jacobi on S (S' rows in VGPRs, G column-major in LDS).
// Outer: phase1 Z = M X (float4), phase2 x' = c - G Z (G rows in VGPRs).
//
// LESSONS (do not regress):
//  - R6: per-thread scalar global reads (stride 160B) are uncoalesced — keep ALL global
//    access as lane-contiguous float4.
//  - R6/R7: `#pragma unroll` on the INNER/OUTER sweep loops explodes live registers
//    -> scratch spills. Keep sweep loops ROLLED.
//  - R8 (REGRESSION 67->85 us): explicit per-k LDS reads in the hot loop quadrupled
//    LDS issue. Keep the sr0..sr3 register structure.
//  - R9 (REGRESSION 67->111 us, counters finally visible): VGPR_Count=128 (default
//    cap for 400-thread launch_bounds) cannot hold sr(160)+gr(80); the float4
//    ds_read_b128 gathers (quad-aligned VGPR tuples) broke the compiler's
//    LDS-rematerialization escape hatch -> full scratch spill: FETCH 9.6 MB,
//    WRITE 18 MB, dispatch 58 us.
//  - R10: __launch_bounds__(NTH, 2) -> min 2 waves/EU -> VGPR cap 256. A 7-wave
//    block fits (2/2/2/1 waves/SIMD at <=256 VGPR). Peak live ~190 regs fits with
//    headroom: sr stays register-resident, no remat, no spill. 1 block/CU is fine
//    (80 blocks on 256 CUs never stacked anyway).
//  - sGrow: final inner sweep scatters G ROW-major (4 one-time scalar writes);
//    outer gather = 20 ds_read_b128 (was 80 scalar). Pad 11 float4/row (stride
//    176B -> only p,p+8,p+16 alias; pad 12 would be 10-way).
__global__ __launch_bounds__(NTH, 2) void gliam_solve(
    const float* __restrict__ mat,   // (NSYS, GS, GS)
    const float* __restrict__ val,   // (NSYS, GS, PARAM)
    const float* __restrict__ S,     // (PARAM, PARAM)
    const float* __restrict__ Ng,    // (PARAM, PARAM)
    float* __restrict__ out)         // (NSYS, GS, PARAM)
{
    __shared__ float4 sSoff[PARAM * 11];   // D^-1 S, diag zeroed, rows padded to 44 floats
    __shared__ float4 sNgP [PARAM * 11];   // raw Ng, padded
    __shared__ float  sRD  [PARAM];        // 1 / S[p][p]
    __shared__ float  sM   [GS * GS];
    __shared__ float4 sGc  [2][PARAM * 11]; // G column-major: col u at [u*11 .. u*11+9]
    __shared__ float4 sGrow[PARAM * 11];    // final G row-major: row r at [r*11 .. r*11+9]
    __shared__ float4 sXv  [2][NLOC / 4];   // state X (also c-iteration buffer)
    __shared__ float4 sZ   [NLOC / 4];      // Z = M·X

    const int sys = blockIdx.x;
    const int t   = threadIdx.x;
    const int pb  = t % 10;   // float4 row-block: rows 4pb..4pb+3
    const int u   = t / 10;   // 0..39: G column index; (u<20) also c system-row

    // ---- stage (coalesced float4) + fold D^-1 into S rows ----
    {
        const float rd = 1.0f / S[u * PARAM + u];    // 40 distinct addrs, L1 broadcast
        float4 a = ((const float4*)S)[t];            // row u, float4 block pb (coalesced)
        a.x *= rd; a.y *= rd; a.z *= rd; a.w *= rd;
        if (pb == (u >> 2)) ((float*)&a)[u & 3] = 0.0f;   // zero diagonal entry
        sSoff[u * 11 + pb] = a;
        sNgP [u * 11 + pb] = ((const float4*)Ng)[t]; // coalesced
    }
    if (t < PARAM) sRD[t] = 1.0f / S[t * PARAM + t];
    sM[t] = mat[sys * GS * GS + t];                  // GS*GS == NTH == 400, coalesced
    __syncthreads();

    // ---- per-thread registers: S' rows 4pb..4pb+3; Ngd/Vd constants for column u ----
    float4 sr0[10], sr1[10], sr2[10], sr3[10];
    float4 ngd, vd = make_float4(0.f, 0.f, 0.f, 0.f);
    {
        #pragma unroll
        for (int k = 0; k < 10; ++k) {
            sr0[k] = sSoff[(4*pb+0)*11 + k];
            sr1[k] = sSoff[(4*pb+1)*11 + k];
            sr2[k] = sSoff[(4*pb+2)*11 + k];
            sr3[k] = sSoff[(4*pb+3)*11 + k];
        }
        const float* Ngf = (const float*)sNgP;       // LDS transpose-gather (once)
        const float rd0 = sRD[4*pb+0], rd1 = sRD[4*pb+1],
                    rd2 = sRD[4*pb+2], rd3 = sRD[4*pb+3];
        ngd.x = Ngf[(4*pb+0)*44 + u] * rd0;
        ngd.y = Ngf[(4*pb+1)*44 + u] * rd1;
        ngd.z = Ngf[(4*pb+2)*44 + u] * rd2;
        ngd.w = Ngf[(4*pb+3)*44 + u] * rd3;
        sGc[0][u*11 + pb] = ngd;                     // G0 = D^-1 Ng (column-major)
        if (u < GS) {
            const float4 v4 = *(const float4*)&val[sys*NLOC + u*PARAM + 4*pb]; // coalesced
            vd.x = v4.x * rd0; vd.y = v4.y * rd1; vd.z = v4.z * rd2; vd.w = v4.w * rd3;
            sXv[0][u*10 + pb] = vd;                  // c0 = D^-1 v
        }
    }
    __syncthreads();

    // ---- inner sweeps (ROLLED): G <- Ngd - S'off G ;  c <- Vd - S'off c ----
    for (int s = 0; s < INNER; ++s) {
        const int cur = s & 1, nxt = cur ^ 1;
        float4 accG = ngd;
        float4 accC = vd;
        const float4* gcol = &sGc[cur][u * 11];
        #pragma unroll
        for (int k = 0; k < 10; ++k) {
            const float4 g = gcol[k];
            accG.x -= sr0[k].x*g.x + sr0[k].y*g.y + sr0[k].z*g.z + sr0[k].w*g.w;
            accG.y -= sr1[k].x*g.x + sr1[k].y*g.y + sr1[k].z*g.z + sr1[k].w*g.w;
            accG.z -= sr2[k].x*g.x + sr2[k].y*g.y + sr2[k].z*g.z + sr2[k].w*g.w;
            accG.w -= sr3[k].x*g.x + sr3[k].y*g.y + sr3[k].z*g.z + sr3[k].w*g.w;
        }
        if (u < GS) {
            const float4* ccol = &sXv[cur][u * 10];
            #pragma unroll
            for (int k = 0; k < 10; ++k) {
                const float4 c = ccol[k];
                accC.x -= sr0[k].x*c.x + sr0[k].y*c.y + sr0[k].z*c.z + sr0[k].w*c.w;
                accC.y -= sr1[k].x*c.x + sr1[k].y*c.y + sr1[k].z*c.z + sr1[k].w*c.w;
                accC.z -= sr2[k].x*c.x + sr2[k].y*c.y + sr2[k].z*c.z + sr2[k].w*c.w;
                accC.w -= sr3[k].x*c.x + sr3[k].y*c.y + sr3[k].z*c.z + sr3[k].w*c.w;
            }
        }
        if (s < INNER - 1) {
            sGc[nxt][u*11 + pb] = accG;              // column-major for next sweep
        } else {
            float* Gr = (float*)sGrow;               // final sweep: row-major scatter
            Gr[(4*pb+0)*44 + u] = accG.x;
            Gr[(4*pb+1)*44 + u] = accG.y;
            Gr[(4*pb+2)*44 + u] = accG.z;
            Gr[(4*pb+3)*44 + u] = accG.w;
        }
        if (u < GS) sXv[nxt][u*10 + pb] = accC;
        __syncthreads();
    }
    const int fin = INNER & 1;   // final c buffer index (== 1 for odd INNER)

    // ---- outer-loop registers: G rows p, p+20 (float4 reads); c values; M row ----
    const int i = t / GS;        // block-row 0..19
    const int p = t % GS;        // component 0..19; partner p+20
    float4 gr0[10], gr1[10];
    #pragma unroll
    for (int k = 0; k < 10; ++k) {
        gr0[k] = sGrow[ p      * 11 + k];
        gr1[k] = sGrow[(p + 20)* 11 + k];
    }
    const float c0 = ((const float*)sXv[fin])[i*PARAM + p];
    const float c1 = ((const float*)sXv[fin])[i*PARAM + p + 20];
    float4 mrow4[5];
    if (t < 200) {
        const int zi = t / 10;
        #pragma unroll
        for (int k = 0; k < 5; ++k) mrow4[k] = *(const float4*)&sM[zi*GS + 4*k];
    }
    // (reads only — all data final behind the last inner barrier; x0 = c in sXv[fin])

    int cur = fin;
    for (int it = 0; it < OUTER; ++it) {   // ROLLED (see header note)
        // phase 1: Z[zi][cc4] = sum_j M[zi,j] * X[j][cc4]  (j order preserved)
        if (t < 200) {
            const int zi = t / 10, cc = t - (t/10)*10;
            const float4* X4 = sXv[cur];
            float4 acc = make_float4(0.f, 0.f, 0.f, 0.f);
            #pragma unroll
            for (int jb = 0; jb < 5; ++jb) {
                const float4 m  = mrow4[jb];
                const float4 x0 = X4[(4*jb+0)*10 + cc];
                const float4 x1 = X4[(4*jb+1)*10 + cc];
                const float4 x2 = X4[(4*jb+2)*10 + cc];
                const float4 x3 = X4[(4*jb+3)*10 + cc];
                acc.x += m.x*x0.x; acc.y += m.x*x0.y; acc.z += m.x*x0.z; acc.w += m.x*x0.w;
                acc.x += m.y*x1.x; acc.y += m.y*x1.y; acc.z += m.y*x1.z; acc.w += m.y*x1.w;
                acc.x += m.z*x2.x; acc.y += m.z*x2.y; acc.z += m.z*x2.z; acc.w += m.z*x2.w;
                acc.x += m.w*x3.x; acc.y += m.w*x3.y; acc.z += m.w*x3.z; acc.w += m.w*x3.w;
            }
            sZ[zi*10 + cc] = acc;
        }
        __syncthreads();
        // phase 2: x'_{i,p} = c - Grow_p · Z_i  (two outputs share Z_i reads)
        const float4* Z4 = &sZ[i*10];
        float a0 = 0.f, a1 = 0.f;
        #pragma unroll
        for (int k = 0; k < 10; ++k) {
            const float4 z = Z4[k];
            a0 += gr0[k].x*z.x + gr0[k].y*z.y + gr0[k].z*z.z + gr0[k].w*z.w;
            a1 += gr1[k].x*z.x + gr1[k].y*z.y + gr1[k].z*z.z + gr1[k].w*z.w;
        }
        const float x0n = c0 - a0, x1n = c1 - a1;
        if (it == OUTER - 1) {
            // epilogue: advrelu(lo=-1,hi=1) == clip
            out[sys*NLOC + i*PARAM + p   ] = fminf(fmaxf(x0n, -1.f), 1.f);
            out[sys*NLOC + i*PARAM + p+20] = fminf(fmaxf(x1n, -1.f), 1.f);
        } else {
            ((float*)sXv[cur ^ 1])[i*PARAM + p   ] = x0n;
            ((float*)sXv[cur ^ 1])[i*PARAM + p+20] = x1n;
            __syncthreads();
            cur ^= 1;
        }
    }
}

extern "C" void kernel_launch(void* const* d_in, const int* in_sizes, int n_in,
                              void* d_out, int out_size, void* d_ws, size_t ws_size,
                              hipStream_t stream) {
    const float* mat = (const float*)d_in[0];  // 8*10*20*20 = 32000
    const float* val = (const float*)d_in[1];  // 8*10*20*40 = 64000
    const float* S   = (const float*)d_in[2];  // 40*40
    const float* Ng  = (const float*)d_in[3];  // 40*40
    float* out = (float*)d_out;                // 64000 f32

    gliam_solve<<<NSYS, NTH, 0, stream>>>(mat, val, S, Ng, out);
}

// Round 4
// 68.058 us; speedup vs baseline: 1.6348x; 1.6329x over previous
//
#include <hip/hip_runtime.h>

// Problem constants (match reference)
#define GS    20
#define PARAM 40
#define NSYS  80             // B * A = 8 * 10
#define NLOC  (GS * PARAM)   // 800 unknowns per system
#define NTH   400
#define INNER 5              // Jacobi sweeps for G=S^-1 Ng, c=S^-1 v (||B||~0.33); MUST be odd
#define OUTER 3              // block-preconditioned sweeps (rho ~ 0.15); R6/R7: absmax unchanged

// Solve (I (x) S + M (x) Ng) x = v, then clip to [-1,1].
// Block form, row i:  x_i = S^-1 v_i - (S^-1 Ng) sum_j M[i,j] x_j  =  c_i - G z_i
// Setup (inner): G and c via point-Jacobi on S (S' rows in VGPRs, G column-major in LDS).
// Outer: phase1 Z = M X (float4), phase2 x' = c - G Z (G rows in VGPRs).
//
// LESSONS (do not regress):
//  - R6: per-thread scalar global reads (stride 160B) are uncoalesced — keep ALL global
//    access as lane-contiguous float4.
//  - R6/R7: `#pragma unroll` on the INNER/OUTER sweep loops explodes live registers
//    -> scratch spills. Keep sweep loops ROLLED.
//  - R8 (REGRESSION 67->85 us): explicit per-k LDS reads in the hot loop quadrupled
//    LDS issue. Keep the sr0..sr3 register structure.
//  - R9 (REGRESSION 67->111 us): under the 128-VGPR cap, float4 ds_read_b128 gathers
//    for gr/mrow (quad-aligned VGPR tuples) broke the allocator's LDS-remat escape
//    hatch -> full scratch spill: FETCH 9.6 MB, WRITE 18 MB, solve 58 us. The R0
//    body (column-major G + scalar gathers) is the only structure measured fast
//    under cap 128 — keep it EXACTLY.
//  - R10 (NO-OP): __launch_bounds__(NTH, 2) does NOT raise the cap. min_waves=2
//    with a 7-wave block means the compiler budgets 2 blocks/CU -> 14 waves ->
//    4 waves on some SIMD -> cap = 512/4 = 128 (observed). For "one block owns the
//    SIMD pool" the spelling is min_waves=1: 7 waves -> 2/SIMD -> cap 256.
//  - R11 (this round): exact R0 body + __launch_bounds__(NTH, 1). One-variable
//    experiment: cap 256 => sr stays resident, no remat LDS reads, solve < 14 us;
//    cap still 128 => identical to R0 (~14 us solve). Occupancy 1 block/CU is fine
//    (80 blocks on 256 CUs never stacked).
__global__ __launch_bounds__(NTH, 1) void gliam_solve(
    const float* __restrict__ mat,   // (NSYS, GS, GS)
    const float* __restrict__ val,   // (NSYS, GS, PARAM)
    const float* __restrict__ S,     // (PARAM, PARAM)
    const float* __restrict__ Ng,    // (PARAM, PARAM)
    float* __restrict__ out)         // (NSYS, GS, PARAM)
{
    __shared__ float4 sSoff[PARAM * 11];   // D^-1 S, diag zeroed, rows padded to 44 floats
    __shared__ float4 sNgP [PARAM * 11];   // raw Ng, padded
    __shared__ float  sRD  [PARAM];        // 1 / S[p][p]
    __shared__ float  sM   [GS * GS];
    __shared__ float4 sGc  [2][PARAM * 11]; // G column-major: col u at [u*11 .. u*11+9]
    __shared__ float4 sXv  [2][NLOC / 4];   // state X (also c-iteration buffer)
    __shared__ float4 sZ   [NLOC / 4];      // Z = M·X

    const int sys = blockIdx.x;
    const int t   = threadIdx.x;
    const int pb  = t % 10;   // float4 row-block: rows 4pb..4pb+3
    const int u   = t / 10;   // 0..39: G column index; (u<20) also c system-row

    // ---- stage (coalesced float4) + fold D^-1 into S rows ----
    {
        const float rd = 1.0f / S[u * PARAM + u];    // 40 distinct addrs, L1 broadcast
        float4 a = ((const float4*)S)[t];            // row u, float4 block pb (coalesced)
        a.x *= rd; a.y *= rd; a.z *= rd; a.w *= rd;
        if (pb == (u >> 2)) ((float*)&a)[u & 3] = 0.0f;   // zero diagonal entry
        sSoff[u * 11 + pb] = a;
        sNgP [u * 11 + pb] = ((const float4*)Ng)[t]; // coalesced
    }
    if (t < PARAM) sRD[t] = 1.0f / S[t * PARAM + t];
    sM[t] = mat[sys * GS * GS + t];                  // GS*GS == NTH == 400, coalesced
    __syncthreads();

    // ---- per-thread registers: S' rows 4pb..4pb+3; Ngd/Vd constants for column u ----
    float4 sr0[10], sr1[10], sr2[10], sr3[10];
    float4 ngd, vd = make_float4(0.f, 0.f, 0.f, 0.f);
    {
        #pragma unroll
        for (int k = 0; k < 10; ++k) {
            sr0[k] = sSoff[(4*pb+0)*11 + k];
            sr1[k] = sSoff[(4*pb+1)*11 + k];
            sr2[k] = sSoff[(4*pb+2)*11 + k];
            sr3[k] = sSoff[(4*pb+3)*11 + k];
        }
        const float* Ngf = (const float*)sNgP;       // LDS transpose-gather (once)
        const float rd0 = sRD[4*pb+0], rd1 = sRD[4*pb+1],
                    rd2 = sRD[4*pb+2], rd3 = sRD[4*pb+3];
        ngd.x = Ngf[(4*pb+0)*44 + u] * rd0;
        ngd.y = Ngf[(4*pb+1)*44 + u] * rd1;
        ngd.z = Ngf[(4*pb+2)*44 + u] * rd2;
        ngd.w = Ngf[(4*pb+3)*44 + u] * rd3;
        sGc[0][u*11 + pb] = ngd;                     // G0 = D^-1 Ng (column-major)
        if (u < GS) {
            const float4 v4 = *(const float4*)&val[sys*NLOC + u*PARAM + 4*pb]; // coalesced
            vd.x = v4.x * rd0; vd.y = v4.y * rd1; vd.z = v4.z * rd2; vd.w = v4.w * rd3;
            sXv[0][u*10 + pb] = vd;                  // c0 = D^-1 v
        }
    }
    __syncthreads();

    // ---- inner sweeps (ROLLED): G <- Ngd - S'off G ;  c <- Vd - S'off c ----
    for (int s = 0; s < INNER; ++s) {
        const int cur = s & 1, nxt = cur ^ 1;
        float4 accG = ngd;
        float4 accC = vd;
        const float4* gcol = &sGc[cur][u * 11];
        #pragma unroll
        for (int k = 0; k < 10; ++k) {
            const float4 g = gcol[k];
            accG.x -= sr0[k].x*g.x + sr0[k].y*g.y + sr0[k].z*g.z + sr0[k].w*g.w;
            accG.y -= sr1[k].x*g.x + sr1[k].y*g.y + sr1[k].z*g.z + sr1[k].w*g.w;
            accG.z -= sr2[k].x*g.x + sr2[k].y*g.y + sr2[k].z*g.z + sr2[k].w*g.w;
            accG.w -= sr3[k].x*g.x + sr3[k].y*g.y + sr3[k].z*g.z + sr3[k].w*g.w;
        }
        if (u < GS) {
            const float4* ccol = &sXv[cur][u * 10];
            #pragma unroll
            for (int k = 0; k < 10; ++k) {
                const float4 c = ccol[k];
                accC.x -= sr0[k].x*c.x + sr0[k].y*c.y + sr0[k].z*c.z + sr0[k].w*c.w;
                accC.y -= sr1[k].x*c.x + sr1[k].y*c.y + sr1[k].z*c.z + sr1[k].w*c.w;
                accC.z -= sr2[k].x*c.x + sr2[k].y*c.y + sr2[k].z*c.z + sr2[k].w*c.w;
                accC.w -= sr3[k].x*c.x + sr3[k].y*c.y + sr3[k].z*c.z + sr3[k].w*c.w;
            }
        }
        sGc[nxt][u*11 + pb] = accG;
        if (u < GS) sXv[nxt][u*10 + pb] = accC;
        __syncthreads();
    }
    const int fin = INNER & 1;   // final G / c buffer index (== 1 for odd INNER)

    // ---- outer-loop registers: G rows p, p+20; c values; M row ----
    const int i = t / GS;        // block-row 0..19
    const int p = t % GS;        // component 0..19; partner p+20
    float4 gr0[10], gr1[10];
    {
        const float* Gf = (const float*)sGc[fin];    // G[r][q] at [q*44 + r]
        #pragma unroll
        for (int k = 0; k < 10; ++k) {
            gr0[k].x = Gf[(4*k+0)*44 + p];  gr0[k].y = Gf[(4*k+1)*44 + p];
            gr0[k].z = Gf[(4*k+2)*44 + p];  gr0[k].w = Gf[(4*k+3)*44 + p];
            gr1[k].x = Gf[(4*k+0)*44 + p+20]; gr1[k].y = Gf[(4*k+1)*44 + p+20];
            gr1[k].z = Gf[(4*k+2)*44 + p+20]; gr1[k].w = Gf[(4*k+3)*44 + p+20];
        }
    }
    const float c0 = ((const float*)sXv[fin])[i*PARAM + p];
    const float c1 = ((const float*)sXv[fin])[i*PARAM + p + 20];
    float mrow[GS];
    if (t < 200) {
        const int zi = t / 10;
        #pragma unroll
        for (int j = 0; j < GS; ++j) mrow[j] = sM[zi*GS + j];
    }
    // (reads only — all data final behind the last inner barrier; x0 = c in sXv[fin])

    int cur = fin;
    for (int it = 0; it < OUTER; ++it) {   // ROLLED (see header note)
        // phase 1: Z[zi][cc4] = sum_j M[zi,j] * X[j][cc4]
        if (t < 200) {
            const int zi = t / 10, cc = t - (t/10)*10;
            const float4* X4 = sXv[cur];
            float4 acc = make_float4(0.f, 0.f, 0.f, 0.f);
            #pragma unroll
            for (int j = 0; j < GS; ++j) {
                const float  m = mrow[j];
                const float4 x = X4[j*10 + cc];
                acc.x += m*x.x; acc.y += m*x.y; acc.z += m*x.z; acc.w += m*x.w;
            }
            sZ[t] = acc;
        }
        __syncthreads();
        // phase 2: x'_{i,p} = c - Grow_p · Z_i  (two outputs share Z_i reads)
        const float4* Z4 = &sZ[i*10];
        float a0 = 0.f, a1 = 0.f;
        #pragma unroll
        for (int k = 0; k < 10; ++k) {
            const float4 z = Z4[k];
            a0 += gr0[k].x*z.x + gr0[k].y*z.y + gr0[k].z*z.z + gr0[k].w*z.w;
            a1 += gr1[k].x*z.x + gr1[k].y*z.y + gr1[k].z*z.z + gr1[k].w*z.w;
        }
        const float x0n = c0 - a0, x1n = c1 - a1;
        if (it == OUTER - 1) {
            // epilogue: advrelu(lo=-1,hi=1) == clip
            out[sys*NLOC + i*PARAM + p   ] = fminf(fmaxf(x0n, -1.f), 1.f);
            out[sys*NLOC + i*PARAM + p+20] = fminf(fmaxf(x1n, -1.f), 1.f);
        } else {
            ((float*)sXv[cur ^ 1])[i*PARAM + p   ] = x0n;
            ((float*)sXv[cur ^ 1])[i*PARAM + p+20] = x1n;
            __syncthreads();
            cur ^= 1;
        }
    }
}

extern "C" void kernel_launch(void* const* d_in, const int* in_sizes, int n_in,
                              void* d_out, int out_size, void* d_ws, size_t ws_size,
                              hipStream_t stream) {
    const float* mat = (const float*)d_in[0];  // 8*10*20*20 = 32000
    const float* val = (const float*)d_in[1];  // 8*10*20*40 = 64000
    const float* S   = (const float*)d_in[2];  // 40*40
    const float* Ng  = (const float*)d_in[3];  // 40*40
    float* out = (float*)d_out;                // 64000 f32

    gliam_solve<<<NSYS, NTH, 0, stream>>>(mat, val, S, Ng, out);
}

// Round 5
// 67.978 us; speedup vs baseline: 1.6367x; 1.0012x over previous
//
#include <hip/hip_runtime.h>

// Problem constants (match reference)
#define GS    20
#define PARAM 40
#define NSYS  80             // B * A = 8 * 10
#define NLOC  (GS * PARAM)   // 800 unknowns per system
#define NTH   448            // 7 full waves; 6 columns (60 lanes) per wave, 4 lanes idle
#define INNER 5              // Jacobi sweeps for G=S^-1 Ng, c=S^-1 v (||B||~0.33); MUST be odd
#define OUTER 3              // block-preconditioned sweeps (rho ~ 0.15)

// Solve (I (x) S + M (x) Ng) x = v, then clip to [-1,1].
// Block form, row i:  x_i = S^-1 v_i - (S^-1 Ng) sum_j M[i,j] x_j  =  c_i - G z_i
//
// LESSONS (do not regress):
//  - R6: keep ALL global access lane-contiguous float4.
//  - R6/R7: never unroll the INNER/OUTER sweep loops (reg explosion -> scratch spill).
//  - R8 (67->85): keep the sr0..sr3 register structure; no per-k LDS reads in hot loop.
//  - R9 (67->111): under reg pressure, float4 LDS gathers for gr/mrow (quad-aligned
//    VGPR tuples) broke the allocator -> full spill. Keep gr/mrow gathers SCALAR.
//  - R10/R11: __launch_bounds__ 2nd arg is min waves/EU; (NTH,2) keeps cap 128,
//    (NTH,1) allows 256. Compiler settles at ~112 VGPR, no spill (FETCH 0.5 MB).
//  - R12 (this round): inner-sweep dependency is COLUMN-LOCAL (column u read/written
//    only by its own 10 threads). Remap t -> (w=t/64, lane=t%64), idx = w*60+lane,
//    u=idx/10, pb=idx%10: each column's 10 threads sit in ONE wave -> same-wave
//    in-order DS pipe replaces __syncthreads. Removes 6 of 13 block barriers; waves
//    self-pace through the 5 sweeps. Per-element FP order unchanged (bitwise absmax).
//    Idle lanes get u=39 (light column): in-bounds reads, uniform skip of c-loop in
//    waves 4-6, and never write.
__global__ __launch_bounds__(NTH, 1) void gliam_solve(
    const float* __restrict__ mat,   // (NSYS, GS, GS)
    const float* __restrict__ val,   // (NSYS, GS, PARAM)
    const float* __restrict__ S,     // (PARAM, PARAM)
    const float* __restrict__ Ng,    // (PARAM, PARAM)
    float* __restrict__ out)         // (NSYS, GS, PARAM)
{
    __shared__ float4 sSoff[PARAM * 11];   // D^-1 S, diag zeroed, rows padded to 44 floats
    __shared__ float4 sNgP [PARAM * 11];   // raw Ng, padded
    __shared__ float  sRD  [PARAM];        // 1 / S[p][p]
    __shared__ float  sM   [GS * GS];
    __shared__ float4 sGc  [2][PARAM * 11]; // G column-major: col u at [u*11 .. u*11+9]
    __shared__ float4 sXv  [2][NLOC / 4];   // state X (also c-iteration buffer)
    __shared__ float4 sZ   [NLOC / 4];      // Z = M·X

    const int sys  = blockIdx.x;
    const int t    = threadIdx.x;
    const int lane = t & 63;
    const int w    = t >> 6;
    const int idx  = w * 60 + lane;          // dense work id 0..399 over active lanes
    const bool act = (lane < 60) && (idx < 400);
    const int u    = act ? (idx / 10) : 39;  // column index; idle lanes -> light col 39
    const int pb   = act ? (idx % 10) : 0;   // float4 row-block: rows 4pb..4pb+3

    // ---- stage (coalesced float4 per wave: 60 contiguous) + fold D^-1 into S rows ----
    if (act) {
        const float rd = 1.0f / S[u * PARAM + u];    // 40 distinct addrs, L1 broadcast
        float4 a = ((const float4*)S)[idx];          // row u, float4 block pb
        a.x *= rd; a.y *= rd; a.z *= rd; a.w *= rd;
        if (pb == (u >> 2)) ((float*)&a)[u & 3] = 0.0f;   // zero diagonal entry
        sSoff[u * 11 + pb] = a;
        sNgP [u * 11 + pb] = ((const float4*)Ng)[idx];
        sM[idx] = mat[sys * GS * GS + idx];
    }
    if (t < PARAM) sRD[t] = 1.0f / S[t * PARAM + t];
    __syncthreads();   // sSoff/sNgP/sRD/sM are read cross-wave below

    // ---- per-thread registers: S' rows 4pb..4pb+3; Ngd/Vd constants for column u ----
    float4 sr0[10], sr1[10], sr2[10], sr3[10];
    float4 ngd, vd = make_float4(0.f, 0.f, 0.f, 0.f);
    {
        #pragma unroll
        for (int k = 0; k < 10; ++k) {
            sr0[k] = sSoff[(4*pb+0)*11 + k];
            sr1[k] = sSoff[(4*pb+1)*11 + k];
            sr2[k] = sSoff[(4*pb+2)*11 + k];
            sr3[k] = sSoff[(4*pb+3)*11 + k];
        }
        const float* Ngf = (const float*)sNgP;       // LDS transpose-gather (once)
        const float rd0 = sRD[4*pb+0], rd1 = sRD[4*pb+1],
                    rd2 = sRD[4*pb+2], rd3 = sRD[4*pb+3];
        ngd.x = Ngf[(4*pb+0)*44 + u] * rd0;
        ngd.y = Ngf[(4*pb+1)*44 + u] * rd1;
        ngd.z = Ngf[(4*pb+2)*44 + u] * rd2;
        ngd.w = Ngf[(4*pb+3)*44 + u] * rd3;
        if (act) sGc[0][u*11 + pb] = ngd;            // G0 = D^-1 Ng (column-major)
        if (act && u < GS) {
            const float4 v4 = *(const float4*)&val[sys*NLOC + 4*idx]; // coalesced
            vd.x = v4.x * rd0; vd.y = v4.y * rd1; vd.z = v4.z * rd2; vd.w = v4.w * rd3;
            sXv[0][u*10 + pb] = vd;                  // c0 = D^-1 v
        }
    }
    // NO barrier: sGc[0]/sXv[0] columns are consumed only by their own wave.

    // ---- inner sweeps, BARRIER-FREE (column-local, same-wave DS ordering) ----
    #pragma unroll 1
    for (int s = 0; s < INNER; ++s) {
        const int cur = s & 1, nxt = cur ^ 1;
        float4 accG = ngd;
        float4 accC = vd;
        const float4* gcol = &sGc[cur][u * 11];
        #pragma unroll
        for (int k = 0; k < 10; ++k) {
            const float4 g = gcol[k];
            accG.x -= sr0[k].x*g.x + sr0[k].y*g.y + sr0[k].z*g.z + sr0[k].w*g.w;
            accG.y -= sr1[k].x*g.x + sr1[k].y*g.y + sr1[k].z*g.z + sr1[k].w*g.w;
            accG.z -= sr2[k].x*g.x + sr2[k].y*g.y + sr2[k].z*g.z + sr2[k].w*g.w;
            accG.w -= sr3[k].x*g.x + sr3[k].y*g.y + sr3[k].z*g.z + sr3[k].w*g.w;
        }
        if (u < GS) {   // waves 4-6 skip uniformly (idle lanes carry u=39)
            const float4* ccol = &sXv[cur][u * 10];
            #pragma unroll
            for (int k = 0; k < 10; ++k) {
                const float4 c = ccol[k];
                accC.x -= sr0[k].x*c.x + sr0[k].y*c.y + sr0[k].z*c.z + sr0[k].w*c.w;
                accC.y -= sr1[k].x*c.x + sr1[k].y*c.y + sr1[k].z*c.z + sr1[k].w*c.w;
                accC.z -= sr2[k].x*c.x + sr2[k].y*c.y + sr2[k].z*c.z + sr2[k].w*c.w;
                accC.w -= sr3[k].x*c.x + sr3[k].y*c.y + sr3[k].z*c.z + sr3[k].w*c.w;
            }
        }
        if (act) sGc[nxt][u*11 + pb] = accG;
        if (act && u < GS) sXv[nxt][u*10 + pb] = accC;
    }
    __syncthreads();   // G and c now read cross-wave by the outer phase
    const int fin = INNER & 1;   // final G / c buffer index (== 1 for odd INNER)

    // ---- outer-loop registers: G rows p, p+20 (SCALAR gather — R9); c; M row ----
    const int widx = act ? idx : 0;
    const int i = widx / GS;     // block-row 0..19
    const int p = widx % GS;     // component 0..19; partner p+20
    float4 gr0[10], gr1[10];
    {
        const float* Gf = (const float*)sGc[fin];    // G[r][q] at [q*44 + r]
        #pragma unroll
        for (int k = 0; k < 10; ++k) {
            gr0[k].x = Gf[(4*k+0)*44 + p];  gr0[k].y = Gf[(4*k+1)*44 + p];
            gr0[k].z = Gf[(4*k+2)*44 + p];  gr0[k].w = Gf[(4*k+3)*44 + p];
            gr1[k].x = Gf[(4*k+0)*44 + p+20]; gr1[k].y = Gf[(4*k+1)*44 + p+20];
            gr1[k].z = Gf[(4*k+2)*44 + p+20]; gr1[k].w = Gf[(4*k+3)*44 + p+20];
        }
    }
    const float c0 = ((const float*)sXv[fin])[i*PARAM + p];
    const float c1 = ((const float*)sXv[fin])[i*PARAM + p + 20];
    const bool ph1 = act && (idx < 200);
    float mrow[GS];
    if (ph1) {
        const int zi = idx / 10;
        #pragma unroll
        for (int j = 0; j < GS; ++j) mrow[j] = sM[zi*GS + j];
    }
    // (reads only — all data final behind the post-sweep barrier; x0 = c in sXv[fin])

    int cur = fin;
    #pragma unroll 1
    for (int it = 0; it < OUTER; ++it) {
        // phase 1: Z[zi][cc4] = sum_j M[zi,j] * X[j][cc4]
        if (ph1) {
            const int zi = idx / 10, cc = idx % 10;
            const float4* X4 = sXv[cur];
            float4 acc = make_float4(0.f, 0.f, 0.f, 0.f);
            #pragma unroll
            for (int j = 0; j < GS; ++j) {
                const float  m = mrow[j];
                const float4 x = X4[j*10 + cc];
                acc.x += m*x.x; acc.y += m*x.y; acc.z += m*x.z; acc.w += m*x.w;
            }
            sZ[zi*10 + cc] = acc;
        }
        __syncthreads();
        // phase 2: x'_{i,p} = c - Grow_p · Z_i  (two outputs share Z_i reads)
        const float4* Z4 = &sZ[i*10];
        float a0 = 0.f, a1 = 0.f;
        #pragma unroll
        for (int k = 0; k < 10; ++k) {
            const float4 z = Z4[k];
            a0 += gr0[k].x*z.x + gr0[k].y*z.y + gr0[k].z*z.z + gr0[k].w*z.w;
            a1 += gr1[k].x*z.x + gr1[k].y*z.y + gr1[k].z*z.z + gr1[k].w*z.w;
        }
        const float x0n = c0 - a0, x1n = c1 - a1;
        if (it == OUTER - 1) {
            if (act) {
                // epilogue: advrelu(lo=-1,hi=1) == clip
                out[sys*NLOC + i*PARAM + p   ] = fminf(fmaxf(x0n, -1.f), 1.f);
                out[sys*NLOC + i*PARAM + p+20] = fminf(fmaxf(x1n, -1.f), 1.f);
            }
        } else {
            if (act) {
                ((float*)sXv[cur ^ 1])[i*PARAM + p   ] = x0n;
                ((float*)sXv[cur ^ 1])[i*PARAM + p+20] = x1n;
            }
            __syncthreads();
            cur ^= 1;
        }
    }
}

extern "C" void kernel_launch(void* const* d_in, const int* in_sizes, int n_in,
                              void* d_out, int out_size, void* d_ws, size_t ws_size,
                              hipStream_t stream) {
    const float* mat = (const float*)d_in[0];  // 8*10*20*20 = 32000
    const float* val = (const float*)d_in[1];  // 8*10*20*40 = 64000
    const float* S   = (const float*)d_in[2];  // 40*40
    const float* Ng  = (const float*)d_in[3];  // 40*40
    float* out = (float*)d_out;                // 64000 f32

    gliam_solve<<<NSYS, NTH, 0, stream>>>(mat, val, S, Ng, out);
}